// Round 10
// baseline (266.263 us; speedup 1.0000x reference)
//
#include <hip/hip_runtime.h>
#include <hip/hip_bf16.h>
#include <stdint.h>

// KANLinear: y[b,o] = sum_{d,k} coeff[b,d,k]*values[o,d,k] + xc@skip_w^T + skip_b
//   Vp[o,d*16+k] = values[o,d,k] + grid[k]*skip_w[o,d]   (prep, bf16)
//   y = A @ Vp^T + skip_b  (MFMA GEMM  M=8192 N=256 K=4096)
// Round 10: TLP push - 4 blocks/CU (16 waves, 4/SIMD). BM=64 BN=128 BK=64,
//   KS=4 -> 1024 blocks x 256 thr. Waves 1x4 in N (zero B-load duplication).
//   LDS = A-dbuf 16KB only; launch_bounds(256,4) caps VGPR 128.
//   B direct from L2 (chunk-transposed Vp), 1-deep reg prefetch.
//   Fused finisher (atomic counter + threadfence, 4 arrivals) - no reduce
//   kernel; ks=0 writes out directly, partials only 3x8MB.

#define D_DIM  256
#define O_DIM  256
#define BM     64
#define BN     128
#define BK     64
#define KS     4
#define ITERS  16            // (4096/KS)/BK
#define NTHR   256

typedef __attribute__((ext_vector_type(8))) short bf16x8;
typedef __attribute__((ext_vector_type(4))) float f32x4;

// ---------------------------------------------------------------------------
// Prep (proven R6-R9): Vp chunk-transposed: chunk c = kflat>>3 (16B of 8
// bf16) stored at Vp[(c*256 + o)*8] -> B-fragment load is 256B-coalesced.
// ---------------------------------------------------------------------------
__global__ __launch_bounds__(256) void kan_prep(
    const float* __restrict__ values,   // [O][D][K]
    const float* __restrict__ skip_w,   // [O][D]
    const float* __restrict__ gknots,   // [K]
    unsigned short* __restrict__ Vp)    // 2 MB bf16, chunk-transposed
{
    int tid = blockIdx.x * blockDim.x + threadIdx.x;    // 0..131071
    int e = tid * 8;
    int o = e >> 12;
    int kflat = e & 4095;
    float sw = skip_w[(o << 8) | (kflat >> 4)];
    int kmod = kflat & 15;                              // 0 or 8

    const float4* vp4 = reinterpret_cast<const float4*>(values + e);
    float4 v0 = vp4[0], v1 = vp4[1];
    float f[8] = {v0.x, v0.y, v0.z, v0.w, v1.x, v1.y, v1.z, v1.w};
    unsigned int w[4];
#pragma unroll
    for (int j = 0; j < 4; ++j) {
        float2 ab;
        ab.x = f[2*j]     + gknots[kmod + 2*j]     * sw;
        ab.y = f[2*j + 1] + gknots[kmod + 2*j + 1] * sw;
        __hip_bfloat162 p2 = __float22bfloat162_rn(ab);
        __builtin_memcpy(&w[j], &p2, 4);
    }
    size_t c = (size_t)(kflat >> 3) * 256 + (size_t)o;
    *reinterpret_cast<uint4*>(Vp + c * 8) = make_uint4(w[0], w[1], w[2], w[3]);
}

// ---------------------------------------------------------------------------
// GEMM: BM=64 x BN=128 x BK=64; 4 waves, each owning a 64x32 wave-tile
// (acc[4][2]); A via 16KB LDS dbuf (conflict-free swizzle, proven); B direct
// L2->reg 1-deep prefetch, no duplication across waves. Fused finisher.
// ---------------------------------------------------------------------------
__global__ __launch_bounds__(NTHR, 4) void kan_gemm(
    const float* __restrict__ x,          // [B][D] f32
    const unsigned short* __restrict__ Vp,
    const float* __restrict__ skip_b,     // [O]
    float* __restrict__ part,             // [3][8192][256] f32 (ks=1..3)
    int* __restrict__ cnt,                // [128][2] zeroed per launch
    float* __restrict__ out)              // [8192][256] f32 (ks=0 partial, final)
{
    __shared__ unsigned short As[2][BM * BK];   // 2 x 8 KB
    __shared__ int sflag;

    const int t    = threadIdx.x;
    const int lane = t & 63;
    const int wid  = t >> 6;           // 0..3 -> wave's 32-col slice
    const int l15  = lane & 15;
    const int lhi  = lane >> 4;        // 0..3

    const int bid = (int)blockIdx.x;
    const int ks  = bid & 3;
    const int nt  = (bid >> 2) & 1;
    const int mt  = bid >> 3;                       // 0..127
    const int bm0 = mt * BM;
    const int nc0 = nt * BN;
    const size_t kc0 = (size_t)ks * 128;            // 16B-chunk base

    // A staging: thread -> row ar (0..63), d-group dg (0..3)
    const int ar = t >> 2;
    const int dg = t & 3;
    const float* xp = x + (size_t)(bm0 + ar) * D_DIM + ks * 64 + dg;

    char* arow[2] = { (char*)&As[0][0] + ar * 128, (char*)&As[1][0] + ar * 128 };
    const int cs0 = ((2 * dg)     ^ (ar & 7)) * 16;
    const int cs1 = ((2 * dg + 1) ^ (ar & 7)) * 16;

    // one x value -> 16 bf16 interp coeffs (8 dwords) at knots li, li+1
    auto stageA = [&](int buf, float xv) {
        float xc = fminf(1.f, fmaxf(-1.f, xv));
        float tt = (xc + 1.f) * 7.5f;            // (xc - g0)/h, h = 2/15
        int li = (int)tt;
        li = li > 14 ? 14 : li;
        float w1 = tt - (float)li;
        float2 cw; cw.x = 1.f - w1; cw.y = w1;
        __hip_bfloat162 p2 = __float22bfloat162_rn(cw);   // v_cvt_pk_bf16_f32
        unsigned int pk;
        __builtin_memcpy(&pk, &p2, 4);
        unsigned long long w64 = (unsigned long long)pk << ((li & 1) * 16);
        unsigned int lo = (unsigned int)w64;
        unsigned int hi = (unsigned int)(w64 >> 32);
        int jl = li >> 1;
        unsigned int wd[8];
#pragma unroll
        for (int j = 0; j < 8; ++j)
            wd[j] = (j == jl) ? lo : ((j == jl + 1) ? hi : 0u);
        char* a = arow[buf];
        *reinterpret_cast<uint4*>(a + cs0) = make_uint4(wd[0], wd[1], wd[2], wd[3]);
        *reinterpret_cast<uint4*>(a + cs1) = make_uint4(wd[4], wd[5], wd[6], wd[7]);
    };

    // B fragment loads: frag (kh,ni): chunk kc0 + KT*8 + kh*4 + lhi,
    // col n = nc0 + wid*32 + ni*16 + l15.  4 loads/iter, no wave duplication.
    #define LOADB(BG, KT)                                                      \
        {                                                                      \
            const unsigned short* _b = Vp + (kc0 + (size_t)(KT) * 8) * 2048;   \
            _Pragma("unroll")                                                  \
            for (int kh = 0; kh < 2; ++kh)                                     \
                _Pragma("unroll")                                              \
                for (int ni = 0; ni < 2; ++ni) {                               \
                    int n = nc0 + wid * 32 + ni * 16 + l15;                    \
                    BG[kh * 2 + ni] = *reinterpret_cast<const bf16x8*>(        \
                        _b + ((size_t)((kh * 4 + lhi) * 256 + n)) * 8);        \
                }                                                              \
        }

    // per-thread A-read constants
    int abyte[4], a7[4];
#pragma unroll
    for (int mi = 0; mi < 4; ++mi) {
        int m = mi * 16 + l15;
        abyte[mi] = m * 128;
        a7[mi] = m & 7;
    }

    f32x4 acc[4][2] = {};
    bf16x8 bgA[4], bgB[4];

    // ---- prologue
    float x1 = xp[0];
    LOADB(bgA, 0);
    stageA(0, x1);
    float xn = xp[4];
    asm volatile("s_waitcnt lgkmcnt(0)" ::: "memory");
    __builtin_amdgcn_s_barrier();
    __builtin_amdgcn_sched_barrier(0);

    #define ITERBODY(KT, CUR, BGC, BGN)                                       \
        {                                                                     \
            const bool last = (KT) == ITERS - 1;                              \
            if (!last) LOADB(BGN, (KT) + 1);                                  \
            const char* Ab = (const char*)&As[CUR][0];                        \
            bf16x8 af[4][2];                                                  \
            _Pragma("unroll")                                                 \
            for (int kh = 0; kh < 2; ++kh) {                                  \
                int k8 = kh * 4 + lhi;                                        \
                _Pragma("unroll")                                             \
                for (int mi = 0; mi < 4; ++mi)                                \
                    af[mi][kh] = *reinterpret_cast<const bf16x8*>(            \
                        Ab + abyte[mi] + ((k8 ^ a7[mi]) << 4));               \
            }                                                                 \
            if (!last) {                                                      \
                stageA((CUR) ^ 1, xn);                                        \
                if ((KT) + 2 < ITERS) xn = xp[((KT) + 2) * 4];                \
            }                                                                 \
            __builtin_amdgcn_s_setprio(1);                                    \
            _Pragma("unroll")                                                 \
            for (int mi = 0; mi < 4; ++mi)                                    \
                _Pragma("unroll")                                             \
                for (int ni = 0; ni < 2; ++ni)                                \
                    _Pragma("unroll")                                         \
                    for (int kh = 0; kh < 2; ++kh)                            \
                        acc[mi][ni] = __builtin_amdgcn_mfma_f32_16x16x32_bf16(\
                            af[mi][kh], BGC[kh * 2 + ni], acc[mi][ni], 0,0,0);\
            __builtin_amdgcn_s_setprio(0);                                    \
            if (!last) {                                                      \
                asm volatile("s_waitcnt lgkmcnt(0)" ::: "memory");            \
                __builtin_amdgcn_s_barrier();                                 \
                __builtin_amdgcn_sched_barrier(0);                            \
            }                                                                 \
        }

    for (int t2 = 0; t2 < ITERS / 2; ++t2) {
        ITERBODY(2 * t2,     0, bgA, bgB);
        ITERBODY(2 * t2 + 1, 1, bgB, bgA);
    }
    #undef ITERBODY
    #undef LOADB

    // ---- store this K-slice's partial (ks=0 -> out, else part[ks-1])
    float* dst = (ks == 0) ? out : part + (size_t)(ks - 1) * (8192 * 256);
#pragma unroll
    for (int ni = 0; ni < 2; ++ni) {
        int col = nc0 + wid * 32 + ni * 16 + l15;
#pragma unroll
        for (int mi = 0; mi < 4; ++mi) {
            f32x4 v = acc[mi][ni];
            int row0 = bm0 + mi * 16 + lhi * 4;
#pragma unroll
            for (int r = 0; r < 4; ++r)
                dst[(size_t)(row0 + r) * O_DIM + col] = v[r];
        }
    }

    // ---- fused finisher: 4th arrival for this (mt,nt) combines + bias
    __threadfence();                               // release partial stores
    if (t == 0) sflag = atomicAdd(&cnt[mt * 2 + nt], 1);
    __syncthreads();
    if (sflag == 3) {
        __threadfence();                           // acquire others' stores
        const float* p0 = part;
        const float* p1 = part + (size_t)8192 * 256;
        const float* p2 = part + (size_t)2 * 8192 * 256;
#pragma unroll
        for (int i = 0; i < 8; ++i) {
            int c = t + 256 * i;                   // 0..2047 f32x4 chunks
            int row = bm0 + (c >> 5);
            int col = nc0 + (c & 31) * 4;
            size_t off = (size_t)row * O_DIM + col;
            f32x4 s = *reinterpret_cast<const f32x4*>(out + off);
            s += *reinterpret_cast<const f32x4*>(p0 + off);
            s += *reinterpret_cast<const f32x4*>(p1 + off);
            s += *reinterpret_cast<const f32x4*>(p2 + off);
            s += *reinterpret_cast<const f32x4*>(skip_b + col);
            *reinterpret_cast<f32x4*>(out + off) = s;
        }
    }
}

// ---------------------------------------------------------------------------
// Naive fallback (tiny workspace only) — correct, slow.
// ---------------------------------------------------------------------------
__global__ __launch_bounds__(256) void kan_naive(
    const float* __restrict__ x,
    const unsigned short* __restrict__ Vp,   // chunk-transposed
    const float* __restrict__ skip_b,
    float* __restrict__ out)
{
    int b = blockIdx.x, o = threadIdx.x;
    float acc = skip_b[o];
    for (int d = 0; d < 256; ++d) {
        float xc = fminf(1.f, fmaxf(-1.f, x[(size_t)b * 256 + d]));
        float tt = (xc + 1.f) * 7.5f;
        int li = (int)tt; li = li > 14 ? 14 : li;
        float w1 = tt - (float)li;
        int k0 = d * 16 + li;
        unsigned short u0 = Vp[((size_t)(k0 >> 3) * 256 + o) * 8 + (k0 & 7)];
        int k1 = k0 + 1;
        unsigned short u1 = Vp[((size_t)(k1 >> 3) * 256 + o) * 8 + (k1 & 7)];
        float f0 = __uint_as_float((unsigned)u0 << 16);
        float f1 = __uint_as_float((unsigned)u1 << 16);
        acc += (1.f - w1) * f0 + w1 * f1;
    }
    out[(size_t)b * 256 + o] = acc;
}

extern "C" void kernel_launch(void* const* d_in, const int* in_sizes, int n_in,
                              void* d_out, int out_size, void* d_ws, size_t ws_size,
                              hipStream_t stream) {
    const float* x      = (const float*)d_in[0];   // [8192][256]
    const float* values = (const float*)d_in[1];   // [256][256][16]
    const float* skip_w = (const float*)d_in[2];   // [256][256]
    const float* skip_b = (const float*)d_in[3];   // [256]
    const float* gknots = (const float*)d_in[4];   // [16]
    float* out = (float*)d_out;
    (void)in_sizes; (void)n_in; (void)out_size;

    unsigned short* Vp = (unsigned short*)d_ws;                          // 2 MB
    float* part = (float*)((char*)d_ws + 2u * 1024 * 1024);              // 24 MB
    int* cnt = (int*)((char*)d_ws + 2u * 1024 * 1024
                      + (size_t)3 * 8192 * 256 * sizeof(float));         // 1 KB

    kan_prep<<<dim3(512), dim3(256), 0, stream>>>(values, skip_w, gknots, Vp);

    const size_t need = 2u * 1024 * 1024
                      + (size_t)3 * 8192 * 256 * sizeof(float) + 1024;
    if (ws_size >= need) {
        hipMemsetAsync(cnt, 0, 256 * sizeof(int), stream);
        // 128 mt x 2 nt x 4 ks = 1024 blocks = 4/CU (16 waves/CU, 4/SIMD)
        kan_gemm<<<dim3(1024), dim3(NTHR), 0, stream>>>(
            x, Vp, skip_b, part, cnt, out);
    } else {
        kan_naive<<<dim3(8192), dim3(256), 0, stream>>>(x, Vp, skip_b, out);
    }
}

// Round 11
// 41.068 us; speedup vs baseline: 6.4834x; 6.4834x over previous
//
#include <hip/hip_runtime.h>
#include <hip/hip_bf16.h>
#include <stdint.h>

// KANLinear: y[b,o] = sum_{d,k} coeff[b,d,k]*values[o,d,k] + xc@skip_w^T + skip_b
//   Vp[o,d*16+k] = values[o,d,k] + grid[k]*skip_w[o,d]   (prep, bf16)
//   y = A @ Vp^T + skip_b  (MFMA GEMM  M=8192 N=256 K=4096)
// Round 11: R10 GEMM core (BM=64 BN=128, 1x4 wave split = zero B dup,
//   4 blocks/CU TLP, VGPR ~96 incl AGPR) WITHOUT the fused finisher:
//   R9/R10's regression was 256/1024 device-scope __threadfence() calls
//   (cross-XCD L2 writebacks). Separate reduce kernel (R6-proven) instead.
//   No atomics, no memset, no fences in the hot kernel.

#define D_DIM  256
#define O_DIM  256
#define BM     64
#define BN     128
#define BK     64
#define KS     4
#define ITERS  16            // (4096/KS)/BK
#define NTHR   256

typedef __attribute__((ext_vector_type(8))) short bf16x8;
typedef __attribute__((ext_vector_type(4))) float f32x4;

// ---------------------------------------------------------------------------
// Prep (proven R6-R10): Vp chunk-transposed: chunk c = kflat>>3 (16B of 8
// bf16) stored at Vp[(c*256 + o)*8] -> B-fragment load is 256B-coalesced.
// ---------------------------------------------------------------------------
__global__ __launch_bounds__(256) void kan_prep(
    const float* __restrict__ values,   // [O][D][K]
    const float* __restrict__ skip_w,   // [O][D]
    const float* __restrict__ gknots,   // [K]
    unsigned short* __restrict__ Vp)    // 2 MB bf16, chunk-transposed
{
    int tid = blockIdx.x * blockDim.x + threadIdx.x;    // 0..131071
    int e = tid * 8;
    int o = e >> 12;
    int kflat = e & 4095;
    float sw = skip_w[(o << 8) | (kflat >> 4)];
    int kmod = kflat & 15;                              // 0 or 8

    const float4* vp4 = reinterpret_cast<const float4*>(values + e);
    float4 v0 = vp4[0], v1 = vp4[1];
    float f[8] = {v0.x, v0.y, v0.z, v0.w, v1.x, v1.y, v1.z, v1.w};
    unsigned int w[4];
#pragma unroll
    for (int j = 0; j < 4; ++j) {
        float2 ab;
        ab.x = f[2*j]     + gknots[kmod + 2*j]     * sw;
        ab.y = f[2*j + 1] + gknots[kmod + 2*j + 1] * sw;
        __hip_bfloat162 p2 = __float22bfloat162_rn(ab);
        __builtin_memcpy(&w[j], &p2, 4);
    }
    size_t c = (size_t)(kflat >> 3) * 256 + (size_t)o;
    *reinterpret_cast<uint4*>(Vp + c * 8) = make_uint4(w[0], w[1], w[2], w[3]);
}

// ---------------------------------------------------------------------------
// GEMM: BM=64 x BN=128 x BK=64; 4 waves, each owning a 64x32 wave-tile
// (acc[4][2]); A via 16KB LDS dbuf (conflict-free swizzle); B direct
// L2->reg 1-deep prefetch, zero duplication across waves.
// Grid 1024 = 4 blocks/CU (16 waves/CU, 4/SIMD).
// ---------------------------------------------------------------------------
__global__ __launch_bounds__(NTHR, 4) void kan_gemm(
    const float* __restrict__ x,          // [B][D] f32
    const unsigned short* __restrict__ Vp,
    float* __restrict__ part,             // [3][8192][256] f32 (ks=1..3)
    float* __restrict__ out)              // [8192][256] f32 (ks=0 partial)
{
    __shared__ unsigned short As[2][BM * BK];   // 2 x 8 KB

    const int t    = threadIdx.x;
    const int lane = t & 63;
    const int wid  = t >> 6;           // 0..3 -> wave's 32-col slice
    const int l15  = lane & 15;
    const int lhi  = lane >> 4;        // 0..3

    const int bid = (int)blockIdx.x;
    const int ks  = bid & 3;
    const int nt  = (bid >> 2) & 1;
    const int mt  = bid >> 3;                       // 0..127
    const int bm0 = mt * BM;
    const int nc0 = nt * BN;
    const size_t kc0 = (size_t)ks * 128;            // 16B-chunk base

    // A staging: thread -> row ar (0..63), d-group dg (0..3)
    const int ar = t >> 2;
    const int dg = t & 3;
    const float* xp = x + (size_t)(bm0 + ar) * D_DIM + ks * 64 + dg;

    char* arow[2] = { (char*)&As[0][0] + ar * 128, (char*)&As[1][0] + ar * 128 };
    const int cs0 = ((2 * dg)     ^ (ar & 7)) * 16;
    const int cs1 = ((2 * dg + 1) ^ (ar & 7)) * 16;

    // one x value -> 16 bf16 interp coeffs (8 dwords) at knots li, li+1
    auto stageA = [&](int buf, float xv) {
        float xc = fminf(1.f, fmaxf(-1.f, xv));
        float tt = (xc + 1.f) * 7.5f;            // (xc - g0)/h, h = 2/15
        int li = (int)tt;
        li = li > 14 ? 14 : li;
        float w1 = tt - (float)li;
        float2 cw; cw.x = 1.f - w1; cw.y = w1;
        __hip_bfloat162 p2 = __float22bfloat162_rn(cw);   // v_cvt_pk_bf16_f32
        unsigned int pk;
        __builtin_memcpy(&pk, &p2, 4);
        unsigned long long w64 = (unsigned long long)pk << ((li & 1) * 16);
        unsigned int lo = (unsigned int)w64;
        unsigned int hi = (unsigned int)(w64 >> 32);
        int jl = li >> 1;
        unsigned int wd[8];
#pragma unroll
        for (int j = 0; j < 8; ++j)
            wd[j] = (j == jl) ? lo : ((j == jl + 1) ? hi : 0u);
        char* a = arow[buf];
        *reinterpret_cast<uint4*>(a + cs0) = make_uint4(wd[0], wd[1], wd[2], wd[3]);
        *reinterpret_cast<uint4*>(a + cs1) = make_uint4(wd[4], wd[5], wd[6], wd[7]);
    };

    // B fragment loads: frag (kh,ni): chunk kc0 + KT*8 + kh*4 + lhi,
    // col n = nc0 + wid*32 + ni*16 + l15.  4 loads/iter, no wave duplication.
    #define LOADB(BG, KT)                                                      \
        {                                                                      \
            const unsigned short* _b = Vp + (kc0 + (size_t)(KT) * 8) * 2048;   \
            _Pragma("unroll")                                                  \
            for (int kh = 0; kh < 2; ++kh)                                     \
                _Pragma("unroll")                                              \
                for (int ni = 0; ni < 2; ++ni) {                               \
                    int n = nc0 + wid * 32 + ni * 16 + l15;                    \
                    BG[kh * 2 + ni] = *reinterpret_cast<const bf16x8*>(        \
                        _b + ((size_t)((kh * 4 + lhi) * 256 + n)) * 8);        \
                }                                                              \
        }

    // per-thread A-read constants
    int abyte[4], a7[4];
#pragma unroll
    for (int mi = 0; mi < 4; ++mi) {
        int m = mi * 16 + l15;
        abyte[mi] = m * 128;
        a7[mi] = m & 7;
    }

    f32x4 acc[4][2] = {};
    bf16x8 bgA[4], bgB[4];

    // ---- prologue
    float x1 = xp[0];
    LOADB(bgA, 0);
    stageA(0, x1);
    float xn = xp[4];
    asm volatile("s_waitcnt lgkmcnt(0)" ::: "memory");
    __builtin_amdgcn_s_barrier();
    __builtin_amdgcn_sched_barrier(0);

    #define ITERBODY(KT, CUR, BGC, BGN)                                       \
        {                                                                     \
            const bool last = (KT) == ITERS - 1;                              \
            if (!last) LOADB(BGN, (KT) + 1);                                  \
            const char* Ab = (const char*)&As[CUR][0];                        \
            bf16x8 af[4][2];                                                  \
            _Pragma("unroll")                                                 \
            for (int kh = 0; kh < 2; ++kh) {                                  \
                int k8 = kh * 4 + lhi;                                        \
                _Pragma("unroll")                                             \
                for (int mi = 0; mi < 4; ++mi)                                \
                    af[mi][kh] = *reinterpret_cast<const bf16x8*>(            \
                        Ab + abyte[mi] + ((k8 ^ a7[mi]) << 4));               \
            }                                                                 \
            if (!last) {                                                      \
                stageA((CUR) ^ 1, xn);                                        \
                if ((KT) + 2 < ITERS) xn = xp[((KT) + 2) * 4];                \
            }                                                                 \
            __builtin_amdgcn_s_setprio(1);                                    \
            _Pragma("unroll")                                                 \
            for (int mi = 0; mi < 4; ++mi)                                    \
                _Pragma("unroll")                                             \
                for (int ni = 0; ni < 2; ++ni)                                \
                    _Pragma("unroll")                                         \
                    for (int kh = 0; kh < 2; ++kh)                            \
                        acc[mi][ni] = __builtin_amdgcn_mfma_f32_16x16x32_bf16(\
                            af[mi][kh], BGC[kh * 2 + ni], acc[mi][ni], 0,0,0);\
            __builtin_amdgcn_s_setprio(0);                                    \
            if (!last) {                                                      \
                asm volatile("s_waitcnt lgkmcnt(0)" ::: "memory");            \
                __builtin_amdgcn_s_barrier();                                 \
                __builtin_amdgcn_sched_barrier(0);                            \
            }                                                                 \
        }

    for (int t2 = 0; t2 < ITERS / 2; ++t2) {
        ITERBODY(2 * t2,     0, bgA, bgB);
        ITERBODY(2 * t2 + 1, 1, bgB, bgA);
    }
    #undef ITERBODY
    #undef LOADB

    // ---- store this K-slice's partial (ks=0 -> out, else part[ks-1])
    float* dst = (ks == 0) ? out : part + (size_t)(ks - 1) * (8192 * 256);
#pragma unroll
    for (int ni = 0; ni < 2; ++ni) {
        int col = nc0 + wid * 32 + ni * 16 + l15;
#pragma unroll
        for (int mi = 0; mi < 4; ++mi) {
            f32x4 v = acc[mi][ni];
            int row0 = bm0 + mi * 16 + lhi * 4;
#pragma unroll
            for (int r = 0; r < 4; ++r)
                dst[(size_t)(row0 + r) * O_DIM + col] = v[r];
        }
    }
}

// ---------------------------------------------------------------------------
// Reduce: out += part[0..2] + skip_b  (vectorized f32x4)
// ---------------------------------------------------------------------------
__global__ __launch_bounds__(256) void kan_reduce(
    const float* __restrict__ part,   // [3][8192][256]
    const float* __restrict__ skip_b, // [256]
    float* __restrict__ out)          // [8192][256] (holds ks=0 partial)
{
    size_t i4 = (size_t)blockIdx.x * 256 + threadIdx.x;   // float4 index
    size_t e = i4 * 4;
    f32x4 s = *reinterpret_cast<const f32x4*>(out + e);
    s += *reinterpret_cast<const f32x4*>(&skip_b[e & 255]);
    s += *reinterpret_cast<const f32x4*>(part + e);
    s += *reinterpret_cast<const f32x4*>(part + (size_t)8192 * 256 + e);
    s += *reinterpret_cast<const f32x4*>(part + (size_t)2 * 8192 * 256 + e);
    *reinterpret_cast<f32x4*>(out + e) = s;
}

// ---------------------------------------------------------------------------
// Naive fallback (tiny workspace only) — correct, slow.
// ---------------------------------------------------------------------------
__global__ __launch_bounds__(256) void kan_naive(
    const float* __restrict__ x,
    const unsigned short* __restrict__ Vp,   // chunk-transposed
    const float* __restrict__ skip_b,
    float* __restrict__ out)
{
    int b = blockIdx.x, o = threadIdx.x;
    float acc = skip_b[o];
    for (int d = 0; d < 256; ++d) {
        float xc = fminf(1.f, fmaxf(-1.f, x[(size_t)b * 256 + d]));
        float tt = (xc + 1.f) * 7.5f;
        int li = (int)tt; li = li > 14 ? 14 : li;
        float w1 = tt - (float)li;
        int k0 = d * 16 + li;
        unsigned short u0 = Vp[((size_t)(k0 >> 3) * 256 + o) * 8 + (k0 & 7)];
        int k1 = k0 + 1;
        unsigned short u1 = Vp[((size_t)(k1 >> 3) * 256 + o) * 8 + (k1 & 7)];
        float f0 = __uint_as_float((unsigned)u0 << 16);
        float f1 = __uint_as_float((unsigned)u1 << 16);
        acc += (1.f - w1) * f0 + w1 * f1;
    }
    out[(size_t)b * 256 + o] = acc;
}

extern "C" void kernel_launch(void* const* d_in, const int* in_sizes, int n_in,
                              void* d_out, int out_size, void* d_ws, size_t ws_size,
                              hipStream_t stream) {
    const float* x      = (const float*)d_in[0];   // [8192][256]
    const float* values = (const float*)d_in[1];   // [256][256][16]
    const float* skip_w = (const float*)d_in[2];   // [256][256]
    const float* skip_b = (const float*)d_in[3];   // [256]
    const float* gknots = (const float*)d_in[4];   // [16]
    float* out = (float*)d_out;
    (void)in_sizes; (void)n_in; (void)out_size;

    unsigned short* Vp = (unsigned short*)d_ws;                          // 2 MB
    float* part = (float*)((char*)d_ws + 2u * 1024 * 1024);              // 24 MB

    kan_prep<<<dim3(512), dim3(256), 0, stream>>>(values, skip_w, gknots, Vp);

    const size_t need = 2u * 1024 * 1024
                      + (size_t)3 * 8192 * 256 * sizeof(float);
    if (ws_size >= need) {
        // 128 mt x 2 nt x 4 ks = 1024 blocks = 4/CU (16 waves/CU, 4/SIMD).
        // bid%8 = (nt,ks) -> default XCD round-robin gives each XCD one
        // Vp slice resident in its L2.
        kan_gemm<<<dim3(1024), dim3(NTHR), 0, stream>>>(x, Vp, part, out);
        kan_reduce<<<dim3(2048), dim3(256), 0, stream>>>(part, skip_b, out);
    } else {
        kan_naive<<<dim3(8192), dim3(256), 0, stream>>>(x, Vp, skip_b, out);
    }
}

// Round 12
// 40.817 us; speedup vs baseline: 6.5233x; 1.0061x over previous
//
#include <hip/hip_runtime.h>
#include <hip/hip_bf16.h>
#include <stdint.h>

// KANLinear: y[b,o] = sum_{d,k} coeff[b,d,k]*values[o,d,k] + xc@skip_w^T + skip_b
//   Vp[o,d*16+k] = values[o,d,k] + grid[k]*skip_w[o,d]   (prep, bf16)
//   y = A @ Vp^T + skip_b  (MFMA GEMM  M=8192 N=256 K=4096)
// Round 12: shrink the serialized pipe SUM (R11 post-mortem: pipes run
//   ~serialized; sum was ~30us). (1) KSPLIT=1: no partials, no reduce
//   kernel (-7us fixed, -24MB writes). (2) BM=BN=64, 2x2 wave split:
//   A-LDS reads halve (16/blk-iter), B stays L2-direct (dup x2, headroom).
//   (3) no s_setprio (hurts lockstep GEMM, m190). (4) XCD swizzle: 4
//   nt-blocks of one mt share an XCD (x read once from HBM).

#define D_DIM  256
#define O_DIM  256
#define BM     64
#define BN     64
#define ITERS  64            // K=4096 / BK=64
#define NTHR   256

typedef __attribute__((ext_vector_type(8))) short bf16x8;
typedef __attribute__((ext_vector_type(4))) float f32x4;

// ---------------------------------------------------------------------------
// Prep (proven R6-R11): Vp chunk-transposed: chunk c = kflat>>3 (16B of 8
// bf16) stored at Vp[(c*256 + o)*8] -> B-fragment load is 256B-coalesced.
// ---------------------------------------------------------------------------
__global__ __launch_bounds__(256) void kan_prep(
    const float* __restrict__ values,   // [O][D][K]
    const float* __restrict__ skip_w,   // [O][D]
    const float* __restrict__ gknots,   // [K]
    unsigned short* __restrict__ Vp)    // 2 MB bf16, chunk-transposed
{
    int tid = blockIdx.x * blockDim.x + threadIdx.x;    // 0..131071
    int e = tid * 8;
    int o = e >> 12;
    int kflat = e & 4095;
    float sw = skip_w[(o << 8) | (kflat >> 4)];
    int kmod = kflat & 15;                              // 0 or 8

    const float4* vp4 = reinterpret_cast<const float4*>(values + e);
    float4 v0 = vp4[0], v1 = vp4[1];
    float f[8] = {v0.x, v0.y, v0.z, v0.w, v1.x, v1.y, v1.z, v1.w};
    unsigned int w[4];
#pragma unroll
    for (int j = 0; j < 4; ++j) {
        float2 ab;
        ab.x = f[2*j]     + gknots[kmod + 2*j]     * sw;
        ab.y = f[2*j + 1] + gknots[kmod + 2*j + 1] * sw;
        __hip_bfloat162 p2 = __float22bfloat162_rn(ab);
        __builtin_memcpy(&w[j], &p2, 4);
    }
    size_t c = (size_t)(kflat >> 3) * 256 + (size_t)o;
    *reinterpret_cast<uint4*>(Vp + c * 8) = make_uint4(w[0], w[1], w[2], w[3]);
}

// ---------------------------------------------------------------------------
// GEMM: BM=64 x BN=64 x BK=64; 4 waves in 2x2, wave-tile 32x32 (acc[2][2]).
// A via 16KB LDS dbuf (conflict-free swizzle); B direct L2->reg 1-deep
// prefetch (2x dup across row-waves). KS=1: direct out + bias, no partials.
// Grid 512 = 2 blocks/CU.
// ---------------------------------------------------------------------------
__global__ __launch_bounds__(NTHR, 2) void kan_gemm(
    const float* __restrict__ x,          // [B][D] f32
    const unsigned short* __restrict__ Vp,
    const float* __restrict__ skip_b,     // [O]
    float* __restrict__ out)              // [B][O] f32
{
    __shared__ unsigned short As[2][BM * 64];   // 2 x 8 KB

    const int t    = threadIdx.x;
    const int lane = t & 63;
    const int wid  = t >> 6;
    const int wr   = wid >> 1;         // 0..1 row half (32 rows)
    const int wc   = wid & 1;          // 0..1 col half (32 cols)
    const int l15  = lane & 15;
    const int lhi  = lane >> 4;        // 0..3

    // XCD swizzle: xcd = l&7 fixed by hardware round-robin; put the 4
    // nt-blocks of one mt on one XCD: nt = bits[3:4], mt = bits[0:2]|[5:8]<<3
    const int l   = (int)blockIdx.x;
    const int nt  = (l >> 3) & 3;
    const int mt  = (l & 7) | ((l >> 5) << 3);      // 0..127
    const int bm0 = mt * BM;
    const int nc0 = nt * BN;

    // A staging: thread -> row ar (0..63), d-group dg (0..3)
    const int ar = t >> 2;
    const int dg = t & 3;
    const float* xp = x + (size_t)(bm0 + ar) * D_DIM + dg;

    char* arow[2] = { (char*)&As[0][0] + ar * 128, (char*)&As[1][0] + ar * 128 };
    const int cs0 = ((2 * dg)     ^ (ar & 7)) * 16;
    const int cs1 = ((2 * dg + 1) ^ (ar & 7)) * 16;

    // one x value -> 16 bf16 interp coeffs (8 dwords) at knots li, li+1
    auto stageA = [&](int buf, float xv) {
        float xc = fminf(1.f, fmaxf(-1.f, xv));
        float tt = (xc + 1.f) * 7.5f;            // (xc - g0)/h, h = 2/15
        int li = (int)tt;
        li = li > 14 ? 14 : li;
        float w1 = tt - (float)li;
        float2 cw; cw.x = 1.f - w1; cw.y = w1;
        __hip_bfloat162 p2 = __float22bfloat162_rn(cw);   // v_cvt_pk_bf16_f32
        unsigned int pk;
        __builtin_memcpy(&pk, &p2, 4);
        unsigned long long w64 = (unsigned long long)pk << ((li & 1) * 16);
        unsigned int lo = (unsigned int)w64;
        unsigned int hi = (unsigned int)(w64 >> 32);
        int jl = li >> 1;
        unsigned int wd[8];
#pragma unroll
        for (int j = 0; j < 8; ++j)
            wd[j] = (j == jl) ? lo : ((j == jl + 1) ? hi : 0u);
        char* a = arow[buf];
        *reinterpret_cast<uint4*>(a + cs0) = make_uint4(wd[0], wd[1], wd[2], wd[3]);
        *reinterpret_cast<uint4*>(a + cs1) = make_uint4(wd[4], wd[5], wd[6], wd[7]);
    };

    // B fragment loads: frag (kh,ni): chunk KT*8 + kh*4 + lhi,
    // col n = nc0 + wc*32 + ni*16 + l15.
    #define LOADB(BG, KT)                                                      \
        {                                                                      \
            const unsigned short* _b = Vp + (size_t)(KT) * 8 * 2048;           \
            _Pragma("unroll")                                                  \
            for (int kh = 0; kh < 2; ++kh)                                     \
                _Pragma("unroll")                                              \
                for (int ni = 0; ni < 2; ++ni) {                               \
                    int n = nc0 + wc * 32 + ni * 16 + l15;                     \
                    BG[kh * 2 + ni] = *reinterpret_cast<const bf16x8*>(        \
                        _b + ((size_t)((kh * 4 + lhi) * 256 + n)) * 8);        \
                }                                                              \
        }

    // per-thread A-read constants (rows wr*32 + mi*16 + l15)
    int abyte[2], a7[2];
#pragma unroll
    for (int mi = 0; mi < 2; ++mi) {
        int m = wr * 32 + mi * 16 + l15;
        abyte[mi] = m * 128;
        a7[mi] = m & 7;
    }

    f32x4 acc[2][2] = {};
    bf16x8 bgA[4], bgB[4];

    // ---- prologue
    float x1 = xp[0];
    LOADB(bgA, 0);
    stageA(0, x1);
    float xn = xp[4];
    asm volatile("s_waitcnt lgkmcnt(0)" ::: "memory");
    __builtin_amdgcn_s_barrier();
    __builtin_amdgcn_sched_barrier(0);

    #define ITERBODY(KT, CUR, BGC, BGN)                                       \
        {                                                                     \
            const bool last = (KT) == ITERS - 1;                              \
            if (!last) LOADB(BGN, (KT) + 1);                                  \
            const char* Ab = (const char*)&As[CUR][0];                        \
            bf16x8 af[2][2];                                                  \
            _Pragma("unroll")                                                 \
            for (int kh = 0; kh < 2; ++kh) {                                  \
                int k8 = kh * 4 + lhi;                                        \
                _Pragma("unroll")                                             \
                for (int mi = 0; mi < 2; ++mi)                                \
                    af[mi][kh] = *reinterpret_cast<const bf16x8*>(            \
                        Ab + abyte[mi] + ((k8 ^ a7[mi]) << 4));               \
            }                                                                 \
            if (!last) {                                                      \
                stageA((CUR) ^ 1, xn);                                        \
                if ((KT) + 2 < ITERS) xn = xp[((KT) + 2) * 4];                \
            }                                                                 \
            _Pragma("unroll")                                                 \
            for (int mi = 0; mi < 2; ++mi)                                    \
                _Pragma("unroll")                                             \
                for (int ni = 0; ni < 2; ++ni)                                \
                    _Pragma("unroll")                                         \
                    for (int kh = 0; kh < 2; ++kh)                            \
                        acc[mi][ni] = __builtin_amdgcn_mfma_f32_16x16x32_bf16(\
                            af[mi][kh], BGC[kh * 2 + ni], acc[mi][ni], 0,0,0);\
            if (!last) {                                                      \
                asm volatile("s_waitcnt lgkmcnt(0)" ::: "memory");            \
                __builtin_amdgcn_s_barrier();                                 \
                __builtin_amdgcn_sched_barrier(0);                            \
            }                                                                 \
        }

    for (int t2 = 0; t2 < ITERS / 2; ++t2) {
        ITERBODY(2 * t2,     0, bgA, bgB);
        ITERBODY(2 * t2 + 1, 1, bgB, bgA);
    }
    #undef ITERBODY
    #undef LOADB

    // ---- epilogue: direct store + bias (no partials, no reduce)
#pragma unroll
    for (int ni = 0; ni < 2; ++ni) {
        int col = nc0 + wc * 32 + ni * 16 + l15;
        float sb = skip_b[col];
#pragma unroll
        for (int mi = 0; mi < 2; ++mi) {
            f32x4 v = acc[mi][ni];
            int row0 = bm0 + wr * 32 + mi * 16 + lhi * 4;
#pragma unroll
            for (int r = 0; r < 4; ++r)
                out[(size_t)(row0 + r) * O_DIM + col] = v[r] + sb;
        }
    }
}

// ---------------------------------------------------------------------------
// Naive fallback (tiny workspace only) — correct, slow.
// ---------------------------------------------------------------------------
__global__ __launch_bounds__(256) void kan_naive(
    const float* __restrict__ x,
    const unsigned short* __restrict__ Vp,   // chunk-transposed
    const float* __restrict__ skip_b,
    float* __restrict__ out)
{
    int b = blockIdx.x, o = threadIdx.x;
    float acc = skip_b[o];
    for (int d = 0; d < 256; ++d) {
        float xc = fminf(1.f, fmaxf(-1.f, x[(size_t)b * 256 + d]));
        float tt = (xc + 1.f) * 7.5f;
        int li = (int)tt; li = li > 14 ? 14 : li;
        float w1 = tt - (float)li;
        int k0 = d * 16 + li;
        unsigned short u0 = Vp[((size_t)(k0 >> 3) * 256 + o) * 8 + (k0 & 7)];
        int k1 = k0 + 1;
        unsigned short u1 = Vp[((size_t)(k1 >> 3) * 256 + o) * 8 + (k1 & 7)];
        float f0 = __uint_as_float((unsigned)u0 << 16);
        float f1 = __uint_as_float((unsigned)u1 << 16);
        acc += (1.f - w1) * f0 + w1 * f1;
    }
    out[(size_t)b * 256 + o] = acc;
}

extern "C" void kernel_launch(void* const* d_in, const int* in_sizes, int n_in,
                              void* d_out, int out_size, void* d_ws, size_t ws_size,
                              hipStream_t stream) {
    const float* x      = (const float*)d_in[0];   // [8192][256]
    const float* values = (const float*)d_in[1];   // [256][256][16]
    const float* skip_w = (const float*)d_in[2];   // [256][256]
    const float* skip_b = (const float*)d_in[3];   // [256]
    const float* gknots = (const float*)d_in[4];   // [16]
    float* out = (float*)d_out;
    (void)in_sizes; (void)n_in; (void)out_size;

    unsigned short* Vp = (unsigned short*)d_ws;    // 2 MB

    kan_prep<<<dim3(512), dim3(256), 0, stream>>>(values, skip_w, gknots, Vp);

    if (ws_size >= 2u * 1024 * 1024) {
        // 128 mt x 4 nt = 512 blocks = 2/CU; swizzled so one mt's 4
        // nt-blocks share an XCD (x-tile fetched once from HBM).
        kan_gemm<<<dim3(512), dim3(NTHR), 0, stream>>>(x, Vp, skip_b, out);
    } else {
        kan_naive<<<dim3(8192), dim3(256), 0, stream>>>(x, Vp, skip_b, out);
    }
}